// Round 3
// baseline (1227.728 us; speedup 1.0000x reference)
//
#include <hip/hip_runtime.h>

#define BH_ 32
#define S_ 2048
#define D_ 64
#define NW 8
#define SCALER_ 0.125f

typedef float f32x4 __attribute__((ext_vector_type(4)));
typedef short bf16x8 __attribute__((ext_vector_type(8)));

__device__ __forceinline__ unsigned short f2bf(float x){
  unsigned int u = __builtin_bit_cast(unsigned int, x);
  u += 0x7fffu + ((u >> 16) & 1u);
  return (unsigned short)(u >> 16);
}

__device__ __forceinline__ float bf2f(unsigned short u){
  return __builtin_bit_cast(float, (unsigned int)u << 16);
}

__device__ __forceinline__ bf16x8 pack8(float4 a, float4 b){
  bf16x8 r;
  r[0]=(short)f2bf(a.x); r[1]=(short)f2bf(a.y); r[2]=(short)f2bf(a.z); r[3]=(short)f2bf(a.w);
  r[4]=(short)f2bf(b.x); r[5]=(short)f2bf(b.y); r[6]=(short)f2bf(b.z); r[7]=(short)f2bf(b.w);
  return r;
}

// LDS layout (46656 B total):
//   vt    : [64][264] bf16 (33792 B)  V-chunk transposed
//   ptile : [NW][16][40] bf16 (10240 B) chunk P tile (C-layout -> A-layout + coalesced P store)
//   maskb : 2048 B  per-batch key mask (1 byte/key, packed from int32 input)
//   rsf   : [NW][16] f32, invf: [16] f32
//   ctxb  : [128][66] f32 = 33792 B aliased over vt ONLY (never over ptile!)
__global__ __launch_bounds__(512, 4) void sdpa_kernel(
    const float* __restrict__ Q, const float* __restrict__ K,
    const float* __restrict__ V, const int* __restrict__ M,
    float* __restrict__ out)
{
  __shared__ __align__(16) unsigned char smem[46656];
  unsigned short* vt    = (unsigned short*)smem;
  unsigned int*   vtw   = (unsigned int*)smem;
  short*          ptile = (short*)(smem + 33792);
  unsigned char*  maskb = smem + 44032;
  float* rsf  = (float*)(smem + 46080);
  float* invf = (float*)(smem + 46592);

  const int t = threadIdx.x;
  const int w = t >> 6;
  const int l = t & 63;
  const int m = l & 15;          // MFMA col-lane / A-row
  const int quad = l >> 4;       // MFMA quad

  const int bh = blockIdx.x >> 7;
  const int q0 = (blockIdx.x & 127) << 4;
  const int b  = bh >> 4;        // H = 16

  const float* Qp = Q + ((size_t)bh*S_ + q0)*D_;
  const float* Kp = K + (size_t)bh*S_*D_;
  const float* Vp = V + (size_t)bh*S_*D_;
  float* ctx_out = out + ((size_t)bh*S_ + q0)*D_;
  float* P_out   = out + (size_t)BH_*S_*D_ + ((size_t)bh*S_ + q0)*(size_t)S_;

  // stage mask row (per batch) to LDS. Input is int32 ("integer -> const int*"):
  // 2048 ints per batch -> 2048 bytes in LDS.
  {
    const int4 mi = ((const int4*)(M + (size_t)b*S_))[t];
    unsigned int pk = (mi.x ? 1u : 0u) | ((mi.y ? 1u : 0u) << 8)
                    | ((mi.z ? 1u : 0u) << 16) | ((mi.w ? 1u : 0u) << 24);
    ((unsigned int*)maskb)[t] = pk;
  }

  // Q fragments: A[m][k=quad*8+j], frag0 = d 0..31, frag1 = d 32..63
  bf16x8 qf0, qf1;
  {
    const float* qrow = Qp + m*D_ + quad*8;
    qf0 = pack8(*(const float4*)(qrow),      *(const float4*)(qrow + 4));
    qf1 = pack8(*(const float4*)(qrow + 32), *(const float4*)(qrow + 36));
  }
  __syncthreads();

  // ---------- pass 1: softmax row sums (no max subtraction: scores <= ~7) ----------
  float rsum[4] = {0.f, 0.f, 0.f, 0.f};
  for (int tile = w; tile < 128; tile += NW) {
    const int k0 = tile << 4;
    const float* krow = Kp + (size_t)(k0 + m)*D_ + quad*8;
    bf16x8 kf0 = pack8(*(const float4*)(krow),      *(const float4*)(krow + 4));
    bf16x8 kf1 = pack8(*(const float4*)(krow + 32), *(const float4*)(krow + 36));
    f32x4 c = {0.f, 0.f, 0.f, 0.f};
    c = __builtin_amdgcn_mfma_f32_16x16x32_bf16(qf0, kf0, c, 0, 0, 0);
    c = __builtin_amdgcn_mfma_f32_16x16x32_bf16(qf1, kf1, c, 0, 0, 0);
    const bool mskd = maskb[k0 + m] != 0;
    #pragma unroll
    for (int r = 0; r < 4; r++) {
      float e = mskd ? 0.f : __expf(c[r] * SCALER_);
      rsum[r] += e;
    }
  }
  #pragma unroll
  for (int r = 0; r < 4; r++) {
    float v = rsum[r];
    v += __shfl_xor(v, 1); v += __shfl_xor(v, 2);
    v += __shfl_xor(v, 4); v += __shfl_xor(v, 8);
    if (m == 0) rsf[w*16 + quad*4 + r] = v;
  }
  __syncthreads();
  if (t < 16) {
    float s = 0.f;
    #pragma unroll
    for (int wv = 0; wv < NW; wv++) s += rsf[wv*16 + t];
    invf[t] = 1.0f / s;
  }
  __syncthreads();
  float invq[4];
  #pragma unroll
  for (int r = 0; r < 4; r++) invq[r] = invf[quad*4 + r];

  // ---------- pass 2: recompute scores, stage P in LDS, write P coalesced, PV MFMA ----------
  f32x4 acc[4];
  #pragma unroll
  for (int n = 0; n < 4; n++) acc[n] = (f32x4){0.f, 0.f, 0.f, 0.f};

  const int gg = (t >> 4) & 15;   // d-group for V staging
  const int ph = t >> 8;          // 0..1
  const int pl = t & 15;          // pair-lane: spreads LDS banks

  // P coalesced-store lane mapping (512 threads -> 16 rows x 256 cols)
  const int prow = t >> 5;
  const int pu   = t & 31;
  const int pcol = pu << 3;

  for (int c = 0; c < 8; ++c) {
    const int kc = c << 8;
    __syncthreads();              // A: protect vt from previous chunk's readers
    // stage V chunk transposed to bf16: conflict-free packed-pair writes
    #pragma unroll
    for (int i = 0; i < 4; i++) {
      const int p = pl + 16*(2*i + ph);   // 0..127 (key pair)
      const float4 va = *(const float4*)(Vp + (size_t)(kc + 2*p    )*D_ + 4*gg);
      const float4 vb = *(const float4*)(Vp + (size_t)(kc + 2*p + 1)*D_ + 4*gg);
      const float* vaf = (const float*)&va;
      const float* vbf = (const float*)&vb;
      #pragma unroll
      for (int j = 0; j < 4; j++) {
        unsigned int pk = (unsigned int)f2bf(vaf[j]) | ((unsigned int)f2bf(vbf[j]) << 16);
        vtw[(4*gg + j)*132 + p] = pk;
      }
    }
    __syncthreads();              // B: vt ready

    // this wave's 32 keys of the chunk -> P values into ptile (C-layout rows)
    const int kbase = kc + w*32;
    short* pt = ptile + w*640;
    #pragma unroll
    for (int s2 = 0; s2 < 2; s2++) {
      const int k0 = kbase + (s2 << 4);
      const float* krow = Kp + (size_t)(k0 + m)*D_ + quad*8;
      bf16x8 kf0 = pack8(*(const float4*)(krow),      *(const float4*)(krow + 4));
      bf16x8 kf1 = pack8(*(const float4*)(krow + 32), *(const float4*)(krow + 36));
      f32x4 sc = {0.f, 0.f, 0.f, 0.f};
      sc = __builtin_amdgcn_mfma_f32_16x16x32_bf16(qf0, kf0, sc, 0, 0, 0);
      sc = __builtin_amdgcn_mfma_f32_16x16x32_bf16(qf1, kf1, sc, 0, 0, 0);
      const bool mskd = maskb[k0 + m] != 0;
      #pragma unroll
      for (int r = 0; r < 4; r++) {
        float e  = mskd ? 0.f : __expf(sc[r] * SCALER_);
        float pv = e * invq[r];
        const int row = quad*4 + r;       // C/D layout: row=(lane>>4)*4+reg, col=lane&15
        pt[row*40 + (s2 << 4) + m] = (short)f2bf(pv);
      }
    }
    __syncthreads();              // B2: ptile ready for ALL waves (fixes RAW race)

    // coalesced P store: thread t writes row prow, cols kc+pcol..kc+pcol+7
    {
      const bf16x8 p8 = *(const bf16x8*)(ptile + (pu >> 2)*640 + prow*40 + ((pu & 3) << 3));
      float4 o0, o1;
      o0.x = bf2f((unsigned short)p8[0]); o0.y = bf2f((unsigned short)p8[1]);
      o0.z = bf2f((unsigned short)p8[2]); o0.w = bf2f((unsigned short)p8[3]);
      o1.x = bf2f((unsigned short)p8[4]); o1.y = bf2f((unsigned short)p8[5]);
      o1.z = bf2f((unsigned short)p8[6]); o1.w = bf2f((unsigned short)p8[7]);
      float* dst = P_out + (size_t)prow*S_ + kc + pcol;
      *(float4*)(dst)     = o0;
      *(float4*)(dst + 4) = o1;
    }

    // P (A-layout) from LDS, V^T (B-layout) from vt, 4 d-tiles
    bf16x8 af = *(const bf16x8*)(pt + m*40 + quad*8);
    #pragma unroll
    for (int n = 0; n < 4; n++) {
      bf16x8 bf = *(const bf16x8*)(vt + (size_t)(n*16 + m)*264 + (w*32 + quad*8));
      acc[n] = __builtin_amdgcn_mfma_f32_16x16x32_bf16(af, bf, acc[n], 0, 0, 0);
    }
  }

  // ---------- epilogue: cross-wave context reduction (ctxb aliases vt ONLY) ----------
  __syncthreads();                 // all vt/ptile reads done
  float* ctxb = (float*)smem;      // [128][66] f32 = 33792 B, inside vt region
  #pragma unroll
  for (int n = 0; n < 4; n++) {
    #pragma unroll
    for (int r = 0; r < 4; r++) {
      ctxb[(size_t)(w*16 + quad*4 + r)*66 + n*16 + m] = acc[n][r];
    }
  }
  __syncthreads();
  if (t < 256) {
    const int e4  = t << 2;
    const int row = e4 >> 6;
    const int col = e4 & 63;
    float s0 = 0.f, s1 = 0.f, s2 = 0.f, s3 = 0.f;
    #pragma unroll
    for (int wv = 0; wv < NW; wv++) {
      const float* p = ctxb + (size_t)(wv*16 + row)*66 + col;
      s0 += p[0]; s1 += p[1]; s2 += p[2]; s3 += p[3];
    }
    float4 o; o.x = s0; o.y = s1; o.z = s2; o.w = s3;
    *(float4*)(ctx_out + row*D_ + col) = o;
  }
}

extern "C" void kernel_launch(void* const* d_in, const int* in_sizes, int n_in,
                              void* d_out, int out_size, void* d_ws, size_t ws_size,
                              hipStream_t stream) {
  const float* Q = (const float*)d_in[0];
  const float* K = (const float*)d_in[1];
  const float* V = (const float*)d_in[2];
  const int* M = (const int*)d_in[3];
  float* out = (float*)d_out;
  sdpa_kernel<<<dim3(4096), dim3(512), 0, stream>>>(Q, K, V, M, out);
}